// Round 4
// baseline (115.599 us; speedup 1.0000x reference)
//
#include <hip/hip_runtime.h>

#define NN 2048
#define DD 128
#define HH 4
#define L2E 1.44269504088896f

typedef __attribute__((ext_vector_type(8))) short short8;
typedef __attribute__((ext_vector_type(16))) float f32x16;
typedef __attribute__((ext_vector_type(4))) unsigned uint4v;

static __device__ __forceinline__ unsigned cvtpk(float lo, float hi) {
  unsigned r;
  asm("v_cvt_pk_bf16_f32 %0, %1, %2" : "=v"(r) : "v"(lo), "v"(hi));
  return r;
}
static __device__ __forceinline__ void plswap(unsigned& a, unsigned& b) {
  asm("v_permlane32_swap_b32 %0, %1" : "+v"(a), "+v"(b));
}
static __device__ __forceinline__ float dot4(float4 a, float4 b) {
  return a.x * b.x + a.y * b.y + a.z * b.z + a.w * b.w;
}

// K1: Vt[b*128+d][j] = (Wr @ h^T) bf16 (32x32x16 MFMA), fused:
//   sr = leaky(fr).ar ; rqsr[bh][j] = {rq*log2e (4), sr*log2e, 0,0,0} bf16 row
__global__ __launch_bounds__(256) void k1_proj(
    const float* __restrict__ h, const float* __restrict__ Wr,
    const float* __restrict__ ar, const float* __restrict__ rh,
    const float* __restrict__ Wrt, short* __restrict__ Vt,
    short* __restrict__ rqsr) {
  __shared__ short wr_s[DD * DD];   // 32 KB, 16B-chunk c of row d at c^(d&7)
  __shared__ short h_s[32 * DD];    // 8 KB, same swizzle
  const int t = threadIdx.x;
  const int lane = t & 63, wv = t >> 6;
  const int b = blockIdx.x >> 6;
  const int j0 = (blockIdx.x & 63) * 32;
  {
    const int d = t >> 1, c0 = (t & 1) * 8;
    const float* src = Wr + d * DD + c0 * 8;
#pragma unroll
    for (int c = 0; c < 8; ++c) {
      const float4 x = *(const float4*)(src + c * 8);
      const float4 y = *(const float4*)(src + c * 8 + 4);
      uint4v v = {cvtpk(x.x, x.y), cvtpk(x.z, x.w), cvtpk(y.x, y.y), cvtpk(y.z, y.w)};
      *(uint4v*)(wr_s + d * DD + (((c0 + c) ^ (d & 7)) << 3)) = v;
    }
  }
  {
    const int j = t >> 3, c0 = (t & 7) * 2;
    const float* src = h + (size_t)(b * NN + j0 + j) * DD + c0 * 8;
#pragma unroll
    for (int c = 0; c < 2; ++c) {
      const float4 x = *(const float4*)(src + c * 8);
      const float4 y = *(const float4*)(src + c * 8 + 4);
      uint4v v = {cvtpk(x.x, x.y), cvtpk(x.z, x.w), cvtpk(y.x, y.y), cvtpk(y.z, y.w)};
      *(uint4v*)(h_s + j * DD + (((c0 + c) ^ (j & 7)) << 3)) = v;
    }
  }
  __syncthreads();
  const int l31 = lane & 31, kg = lane >> 5;
  const int rowA = wv * 32 + l31;
  f32x16 acc = {0, 0, 0, 0, 0, 0, 0, 0, 0, 0, 0, 0, 0, 0, 0, 0};
#pragma unroll
  for (int ks = 0; ks < 8; ++ks) {
    const int ch = ks * 2 + kg;
    const short8 a = *(const short8*)(wr_s + rowA * DD + ((ch ^ (rowA & 7)) << 3));
    const short8 bb = *(const short8*)(h_s + l31 * DD + ((ch ^ (l31 & 7)) << 3));
    acc = __builtin_amdgcn_mfma_f32_32x32x16_bf16(a, bb, acc, 0, 0, 0);
  }
  const int hi4 = kg * 4;
  float4 arv[4];
#pragma unroll
  for (int q = 0; q < 4; ++q) arv[q] = *(const float4*)(ar + q * 8 + hi4);
  float srp = 0.f;
  short* vrow = Vt + (size_t)(b * DD + wv * 32) * NN + j0 + l31;
#pragma unroll
  for (int r = 0; r < 16; ++r) {
    const int dloc = (r & 3) + 8 * (r >> 2) + hi4;
    const float v = acc[r];
    const float lv = v > 0.f ? v : 0.01f * v;
    const float arc =
        (r & 3) == 0 ? arv[r >> 2].x : (r & 3) == 1 ? arv[r >> 2].y : (r & 3) == 2 ? arv[r >> 2].z : arv[r >> 2].w;
    srp += lv * arc;
    vrow[(size_t)dloc * NN] = (short)cvtpk(v, v);
  }
  srp += __shfl_xor(srp, 32);
  if (lane < 32) {
    const int j = j0 + lane;
    const float4 r4 = *(const float4*)(rh + (size_t)(b * NN + j) * 4);
    const float4 wt0 = *(const float4*)(Wrt + (wv * 4 + 0) * 4);
    const float4 wt1 = *(const float4*)(Wrt + (wv * 4 + 1) * 4);
    const float4 wt2 = *(const float4*)(Wrt + (wv * 4 + 2) * 4);
    const float4 wt3 = *(const float4*)(Wrt + (wv * 4 + 3) * 4);
    uint4v v = {cvtpk(L2E * dot4(r4, wt0), L2E * dot4(r4, wt1)),
                cvtpk(L2E * dot4(r4, wt2), L2E * dot4(r4, wt3)),
                cvtpk(L2E * srp, 0.f), 0u};
    *(uint4v*)(rqsr + ((size_t)(b * HH + wv) * NN + j) * 8) = v;
  }
}

// K2: flash attention, zero staging. p = exp2(rqsr_j . {rk_i,1}) via score MFMA,
// in-register C->B repack (cvt_pk + permlane32_swap), PV MFMA from Vt.
// 8 waves = 2 i-strips x 4 j-quarters; LDS only for the jh-reduction.
__global__ __launch_bounds__(512) void k2_attn(
    const float* __restrict__ rh, const float* __restrict__ Wrs,
    const short* __restrict__ rqsr, const short* __restrict__ Vt,
    float* __restrict__ h_sa) {
  __shared__ float red[2][3][64 * 17];
  __shared__ float tbuf[2][32 * 36];
  const int t = threadIdx.x;
  const int lane = t & 63, wv = t >> 6;      // 8 waves
  const int strip = wv >> 2, jh = wv & 3;
  const int bh = blockIdx.y, b = bh >> 2, head = bh & 3;
  const int i0 = blockIdx.x * 64 + strip * 32;
  const int l31 = lane & 31, kg = lane >> 5;

  uint4v bk = {0u, 0u, 0u, 0u};
  if (lane < 32) {
    const float4 r4 = *(const float4*)(rh + (size_t)(b * NN + i0 + l31) * 4);
    const float4 ws0 = *(const float4*)(Wrs + (head * 4 + 0) * 4);
    const float4 ws1 = *(const float4*)(Wrs + (head * 4 + 1) * 4);
    const float4 ws2 = *(const float4*)(Wrs + (head * 4 + 2) * 4);
    const float4 ws3 = *(const float4*)(Wrs + (head * 4 + 3) * 4);
    bk[0] = cvtpk(dot4(r4, ws0), dot4(r4, ws1));
    bk[1] = cvtpk(dot4(r4, ws2), dot4(r4, ws3));
    bk[2] = cvtpk(1.f, 0.f);
  }
  const short8 bkf = __builtin_bit_cast(short8, bk);

  const short* vtb = Vt + (size_t)bh * 32 * NN + (size_t)l31 * NN + jh * 512;
  const short* aqp = rqsr + ((size_t)bh * NN + jh * 512 + l31) * 8;
  const f32x16 zero = {0, 0, 0, 0, 0, 0, 0, 0, 0, 0, 0, 0, 0, 0, 0, 0};
  f32x16 acc = zero;
  float lsum = 0.f;
#pragma unroll 4
  for (int jj = 0; jj < 512; jj += 32) {
    const uint4v aqu = *(const uint4v*)(aqp + (size_t)jj * 8);
    const short8 aq = __builtin_bit_cast(short8, aqu);
    const f32x16 sc = __builtin_amdgcn_mfma_f32_32x32x16_bf16(aq, bkf, zero, 0, 0, 0);
    float e[16];
#pragma unroll
    for (int r = 0; r < 16; ++r) e[r] = exp2f(sc[r]);
    const float s0 = (e[0] + e[1]) + (e[2] + e[3]);
    const float s1 = (e[4] + e[5]) + (e[6] + e[7]);
    const float s2 = (e[8] + e[9]) + (e[10] + e[11]);
    const float s3 = (e[12] + e[13]) + (e[14] + e[15]);
    lsum += (s0 + s1) + (s2 + s3);
    unsigned d0 = cvtpk(e[0], e[1]), d1 = cvtpk(e[2], e[3]);
    unsigned d2 = cvtpk(e[4], e[5]), d3 = cvtpk(e[6], e[7]);
    unsigned d4 = cvtpk(e[8], e[9]), d5 = cvtpk(e[10], e[11]);
    unsigned d6 = cvtpk(e[12], e[13]), d7 = cvtpk(e[14], e[15]);
    plswap(d0, d2);
    plswap(d1, d3);
    plswap(d4, d6);
    plswap(d5, d7);
    uint4v b0u = {d0, d1, d2, d3};
    uint4v b1u = {d4, d5, d6, d7};
    const short8 p0 = __builtin_bit_cast(short8, b0u);
    const short8 p1 = __builtin_bit_cast(short8, b1u);
    const short8 va0 = *(const short8*)(vtb + jj + kg * 8);
    const short8 va1 = *(const short8*)(vtb + jj + 16 + kg * 8);
    acc = __builtin_amdgcn_mfma_f32_32x32x16_bf16(va0, p0, acc, 0, 0, 0);
    acc = __builtin_amdgcn_mfma_f32_32x32x16_bf16(va1, p1, acc, 0, 0, 0);
  }
  lsum += __shfl_xor(lsum, 32);
  if (jh != 0) {
    float* rp = &red[strip][jh - 1][lane * 17];
#pragma unroll
    for (int r = 0; r < 16; ++r) rp[r] = acc[r];
    rp[16] = lsum;
  }
  __syncthreads();
  if (jh == 0) {
#pragma unroll
    for (int s = 0; s < 3; ++s) {
      const float* rp = &red[strip][s][lane * 17];
#pragma unroll
      for (int r = 0; r < 16; ++r) acc[r] += rp[r];
      lsum += rp[16];
    }
    const float linv = 1.f / lsum;
    const int hi4 = kg * 4;
#pragma unroll
    for (int r = 0; r < 16; ++r) {
      const int dloc = (r & 3) + 8 * (r >> 2) + hi4;
      tbuf[strip][l31 * 36 + dloc] = acc[r] * linv;
    }
    const int il = lane >> 1, hf = lane & 1;
    const float* tp = &tbuf[strip][il * 36 + hf * 16];
    float* op = h_sa + (size_t)(b * NN + i0 + il) * DD + head * 32 + hf * 16;
#pragma unroll
    for (int qq = 0; qq < 4; ++qq) *(float4*)(op + qq * 4) = *(const float4*)(tp + qq * 4);
  }
}

// K3: fh = h_sa @ Wf^T (32x32x16 MFMA, on-the-fly bf16), +h residual, fused LN.
__global__ __launch_bounds__(256) void k3_final(
    const float* __restrict__ h_sa, const float* __restrict__ h,
    const float* __restrict__ Wf, const float* __restrict__ ln_g,
    const float* __restrict__ ln_b, float* __restrict__ out) {
  __shared__ float2 redln[4][32];
  __shared__ float2 fin[32];
  const int t = threadIdx.x, lane = t & 63, wv = t >> 6;
  const int l31 = lane & 31, kg = lane >> 5;
  const int rbase = blockIdx.x * 32, c0 = wv * 32;
  f32x16 acc = {0, 0, 0, 0, 0, 0, 0, 0, 0, 0, 0, 0, 0, 0, 0, 0};
  const float* ap0 = h_sa + (size_t)(rbase + l31) * DD;
  const float* bp0 = Wf + (size_t)(c0 + l31) * DD;
#pragma unroll
  for (int ks = 0; ks < 8; ++ks) {
    const int ko = ks * 16 + kg * 8;
    const float4 a0 = *(const float4*)(ap0 + ko);
    const float4 a1 = *(const float4*)(ap0 + ko + 4);
    const float4 b0 = *(const float4*)(bp0 + ko);
    const float4 b1 = *(const float4*)(bp0 + ko + 4);
    uint4v au = {cvtpk(a0.x, a0.y), cvtpk(a0.z, a0.w), cvtpk(a1.x, a1.y), cvtpk(a1.z, a1.w)};
    uint4v bu = {cvtpk(b0.x, b0.y), cvtpk(b0.z, b0.w), cvtpk(b1.x, b1.y), cvtpk(b1.z, b1.w)};
    acc = __builtin_amdgcn_mfma_f32_32x32x16_bf16(__builtin_bit_cast(short8, au),
                                                  __builtin_bit_cast(short8, bu), acc, 0, 0, 0);
  }
  const int hi4 = kg * 4;
  float x[16];
#pragma unroll
  for (int r = 0; r < 16; ++r) {
    const int row = (r & 3) + 8 * (r >> 2) + hi4;
    x[r] = acc[r] + h[(size_t)(rbase + row) * DD + c0 + l31];
    float a = x[r], bsq = x[r] * x[r];
#pragma unroll
    for (int o = 1; o < 32; o <<= 1) {
      a += __shfl_xor(a, o);
      bsq += __shfl_xor(bsq, o);
    }
    if (l31 == 0) redln[wv][row] = make_float2(a, bsq);
  }
  __syncthreads();
  if (wv == 0 && lane < 32) {
    float ss = 0.f, qq = 0.f;
#pragma unroll
    for (int w = 0; w < 4; ++w) {
      const float2 p = redln[w][lane];
      ss += p.x;
      qq += p.y;
    }
    const float mu = ss * (1.f / 128.f);
    const float var = qq * (1.f / 128.f) - mu * mu;
    fin[lane] = make_float2(mu, rsqrtf(var + 1e-5f));
  }
  __syncthreads();
  const float g = ln_g[c0 + l31], bb = ln_b[c0 + l31];
#pragma unroll
  for (int r = 0; r < 16; ++r) {
    const int row = (r & 3) + 8 * (r >> 2) + hi4;
    const float2 f = fin[row];
    out[(size_t)(rbase + row) * DD + c0 + l31] = (x[r] - f.x) * f.y * g + bb;
  }
}

extern "C" void kernel_launch(void* const* d_in, const int* in_sizes, int n_in,
                              void* d_out, int out_size, void* d_ws, size_t ws_size,
                              hipStream_t stream) {
  (void)in_sizes; (void)n_in; (void)out_size; (void)ws_size;
  const float* h = (const float*)d_in[0];
  const float* rh = (const float*)d_in[1];
  // d_in[2]=Wl, d_in[4]=al: dead (softmax shift invariance)
  const float* Wr = (const float*)d_in[3];
  const float* ar = (const float*)d_in[5];
  const float* Wrs = (const float*)d_in[6];
  const float* Wrt = (const float*)d_in[7];
  const float* Wf = (const float*)d_in[8];
  const float* ln_g = (const float*)d_in[9];
  const float* ln_b = (const float*)d_in[10];
  float* out = (float*)d_out;

  char* ws = (char*)d_ws;
  short* Vt = (short*)ws;                       // 2 MB: [16 bh][32 d][2048 j]
  short* rqsr = (short*)(ws + (2u << 20));      // 512 KB: [16 bh][2048 j][8]
  float* h_sa = (float*)(ws + (3u << 20));      // 4 MB

  hipLaunchKernelGGL(k1_proj, dim3(256), dim3(256), 0, stream, h, Wr, ar, rh, Wrt, Vt, rqsr);
  hipLaunchKernelGGL(k2_attn, dim3(32, 16), dim3(512), 0, stream, rh, Wrs, rqsr, Vt, h_sa);
  hipLaunchKernelGGL(k3_final, dim3(256), dim3(256), 0, stream, h_sa, h, Wf, ln_g, ln_b, out);
}